// Round 4
// baseline (1049.121 us; speedup 1.0000x reference)
//
#include <hip/hip_runtime.h>

#define C 128
#define EPS 1e-5f
#define SCAN_TILE 4096   // 1024 threads x 4 elements

__device__ __forceinline__ unsigned short bf16_rne(float f) {
    unsigned u = __float_as_uint(f);
    u = (u + 0x7FFFu + ((u >> 16) & 1u)) >> 16;
    return (unsigned short)u;
}
__device__ __forceinline__ float bf16_to_f32(unsigned short h) {
    return __uint_as_float((unsigned)h << 16);
}

// ---------------- fp32 -> bf16 conversion (4 elems/thread) ----------------
__global__ __launch_bounds__(256) void cvt_bf16_kernel(
    const float* __restrict__ in, unsigned short* __restrict__ out, int n4)
{
    int t = blockIdx.x * blockDim.x + threadIdx.x;
    if (t >= n4) return;
    float4 v = ((const float4*)in)[t];
    ushort4 o;
    o.x = bf16_rne(v.x);
    o.y = bf16_rne(v.y);
    o.z = bf16_rne(v.z);
    o.w = bf16_rne(v.w);
    ((ushort4*)out)[t] = o;
}

// ---------------- combined degree count over both edge types ----------------
__global__ __launch_bounds__(256) void count_kernel(
    const int* __restrict__ ei_iu, const int* __restrict__ ei_ui,
    int* __restrict__ cnt, int E, int NU)
{
    int t = blockIdx.x * blockDim.x + threadIdx.x;
    if (t < E)            atomicAdd(&cnt[ei_iu[E + t]], 1);
    else if (t < 2 * E)   atomicAdd(&cnt[NU + ei_ui[E + (t - E)]], 1);
}

// ---------------- 3-phase multiblock exclusive scan ----------------
__global__ __launch_bounds__(1024) void scan_partials(
    const int* __restrict__ cnt, int* __restrict__ partials, int NTOT)
{
    int base = blockIdx.x * SCAN_TILE + threadIdx.x * 4;
    int s = 0;
    #pragma unroll
    for (int k = 0; k < 4; ++k)
        if (base + k < NTOT) s += cnt[base + k];
    #pragma unroll
    for (int off = 32; off > 0; off >>= 1) s += __shfl_xor(s, off, 64);
    __shared__ int ws[16];
    int wave = threadIdx.x >> 6;
    if ((threadIdx.x & 63) == 0) ws[wave] = s;
    __syncthreads();
    if (threadIdx.x == 0) {
        int tot = 0;
        for (int i = 0; i < 16; ++i) tot += ws[i];
        partials[blockIdx.x] = tot;
    }
}

__global__ __launch_bounds__(1024) void scan_spine(
    int* __restrict__ partials, int* __restrict__ rp, int NPART, int NTOT)
{
    __shared__ int lds[1024];
    int t = threadIdx.x;
    lds[t] = (t < NPART) ? partials[t] : 0;
    __syncthreads();
    for (int off = 1; off < 1024; off <<= 1) {
        int v = (t >= off) ? lds[t - off] : 0;
        __syncthreads();
        lds[t] += v;
        __syncthreads();
    }
    if (t < NPART) partials[t] = (t == 0) ? 0 : lds[t - 1];
    if (t == 0) rp[NTOT] = lds[1023];
}

__global__ __launch_bounds__(1024) void scan_write(
    const int* __restrict__ cnt, const int* __restrict__ partials,
    int* __restrict__ rp, int* __restrict__ cur, int NTOT)
{
    __shared__ int lds[1024];
    int t = threadIdx.x;
    int base = blockIdx.x * SCAN_TILE + t * 4;
    int v0 = 0, v1 = 0, v2 = 0, v3 = 0;
    if (base + 0 < NTOT) v0 = cnt[base + 0];
    if (base + 1 < NTOT) v1 = cnt[base + 1];
    if (base + 2 < NTOT) v2 = cnt[base + 2];
    if (base + 3 < NTOT) v3 = cnt[base + 3];
    lds[t] = v0 + v1 + v2 + v3;
    __syncthreads();
    for (int off = 1; off < 1024; off <<= 1) {
        int v = (t >= off) ? lds[t - off] : 0;
        __syncthreads();
        lds[t] += v;
        __syncthreads();
    }
    int p = partials[blockIdx.x] + ((t == 0) ? 0 : lds[t - 1]);
    if (base + 0 < NTOT) { rp[base + 0] = p; cur[base + 0] = p; p += v0; }
    if (base + 1 < NTOT) { rp[base + 1] = p; cur[base + 1] = p; p += v1; }
    if (base + 2 < NTOT) { rp[base + 2] = p; cur[base + 2] = p; p += v2; }
    if (base + 3 < NTOT) { rp[base + 3] = p; cur[base + 3] = p; }
}

// ---------------- combined CSR fill: ONE packed 8B store per edge ----------------
__global__ __launch_bounds__(256) void fill_kernel(
    const int* __restrict__ ei_iu, const float* __restrict__ ew_iu,
    const int* __restrict__ ei_ui, const float* __restrict__ ew_ui,
    int* __restrict__ cur, int2* __restrict__ csr,
    int E, int NU)
{
    int t = blockIdx.x * blockDim.x + threadIdx.x;
    if (t < E) {
        int pos = atomicAdd(&cur[ei_iu[E + t]], 1);
        int2 e;
        e.x = ei_iu[t];
        e.y = __float_as_int(ew_iu[t]);
        csr[pos] = e;
    } else if (t < 2 * E) {
        int k = t - E;
        int pos = atomicAdd(&cur[NU + ei_ui[E + k]], 1);
        int2 e;
        e.x = ei_ui[k];
        e.y = __float_as_int(ew_ui[k]);
        csr[pos] = e;
    }
}

// ---------------- fused gather(bf16)-aggregate + mean + residual(fp32) + LN (+relu) -----
// one 64-lane wave per dst row; 2 edges in flight (one per 32-lane half);
// each half-wave lane cl loads 4 bf16 channels (8B) of its edge's source row.
__global__ __launch_bounds__(256) void sage_ln_kernel(
    const unsigned short* __restrict__ xb_src,  // bf16 gather source [Nsrc*C]
    const float* __restrict__ x_dst,            // fp32 residual      [N*C]
    const int* __restrict__ rp,
    const int2* __restrict__ csr,
    const float* __restrict__ lnw,
    const float* __restrict__ lnb,
    float* __restrict__ out,                    // fp32 [N*C] (may alias x_dst)
    int N, int do_relu)
{
    int row  = blockIdx.x * 4 + (threadIdx.x >> 6);
    int lane = threadIdx.x & 63;
    int sub  = lane >> 5;
    int cl   = lane & 31;
    if (row >= N) return;
    int start = rp[row];
    int end   = rp[row + 1];

    float4 acc = {0.f, 0.f, 0.f, 0.f};
    for (int idx = start + sub; idx < end; idx += 2) {
        int2 e = csr[idx];                       // 8B broadcast within half-wave
        float w = __int_as_float(e.y);
        ushort4 r = ((const ushort4*)(xb_src + (size_t)e.x * C))[cl];
        acc.x += bf16_to_f32(r.x) * w;
        acc.y += bf16_to_f32(r.y) * w;
        acc.z += bf16_to_f32(r.z) * w;
        acc.w += bf16_to_f32(r.w) * w;
    }
    // combine the two half-wave partials
    acc.x += __shfl_xor(acc.x, 32, 64);
    acc.y += __shfl_xor(acc.y, 32, 64);
    acc.z += __shfl_xor(acc.z, 32, 64);
    acc.w += __shfl_xor(acc.w, 32, 64);

    float inv = 1.0f / fmaxf((float)(end - start), 1.0f);
    float4 xd = ((const float4*)(x_dst + (size_t)row * C))[cl];
    float4 v;
    v.x = acc.x * inv + xd.x;
    v.y = acc.y * inv + xd.y;
    v.z = acc.z * inv + xd.z;
    v.w = acc.w * inv + xd.w;

    float sum = v.x + v.y + v.z + v.w;
    float sq  = v.x * v.x + v.y * v.y + v.z * v.z + v.w * v.w;
    #pragma unroll
    for (int off = 16; off > 0; off >>= 1) {
        sum += __shfl_xor(sum, off, 64);
        sq  += __shfl_xor(sq,  off, 64);
    }
    float mu   = sum * (1.0f / C);
    float var  = sq * (1.0f / C) - mu * mu;
    float rstd = rsqrtf(var + EPS);

    float4 wv = ((const float4*)lnw)[cl];
    float4 bv = ((const float4*)lnb)[cl];
    float4 o;
    o.x = (v.x - mu) * rstd * wv.x + bv.x;
    o.y = (v.y - mu) * rstd * wv.y + bv.y;
    o.z = (v.z - mu) * rstd * wv.z + bv.z;
    o.w = (v.w - mu) * rstd * wv.w + bv.w;
    if (do_relu) {
        o.x = fmaxf(o.x, 0.f); o.y = fmaxf(o.y, 0.f);
        o.z = fmaxf(o.z, 0.f); o.w = fmaxf(o.w, 0.f);
    }
    if (sub == 0) ((float4*)(out + (size_t)row * C))[cl] = o;
}

extern "C" void kernel_launch(void* const* d_in, const int* in_sizes, int n_in,
                              void* d_out, int out_size, void* d_ws, size_t ws_size,
                              hipStream_t stream)
{
    const float* x_user = (const float*)d_in[0];
    const float* x_item = (const float*)d_in[1];
    const float* ew_ui  = (const float*)d_in[2];
    const float* ew_iu  = (const float*)d_in[3];
    const float* lnwu0  = (const float*)d_in[4];
    const float* lnbu0  = (const float*)d_in[5];
    const float* lnwu1  = (const float*)d_in[6];
    const float* lnbu1  = (const float*)d_in[7];
    const float* lnwi0  = (const float*)d_in[8];
    const float* lnbi0  = (const float*)d_in[9];
    const float* lnwi1  = (const float*)d_in[10];
    const float* lnbi1  = (const float*)d_in[11];
    const int*   ei_ui  = (const int*)d_in[12];  // src=user, dst=item
    const int*   ei_iu  = (const int*)d_in[13];  // src=item, dst=user

    const int NU = in_sizes[0] / C;
    const int NI = in_sizes[1] / C;
    const int E  = in_sizes[2];
    const int NTOT = NU + NI;

    float* out   = (float*)d_out;
    float* out_u = out;
    float* out_i = out + (size_t)NU * C;

    // ---- ws layout (~79 MB) ----
    char* p = (char*)d_ws;
    int2*  csr = (int2*)p;               p += (size_t)2 * E * sizeof(int2);
    unsigned short* ub = (unsigned short*)p;  p += (size_t)NU * C * sizeof(unsigned short);
    unsigned short* ib = (unsigned short*)p;  p += (size_t)NI * C * sizeof(unsigned short);
    int*   cnt      = (int*)p;           p += (size_t)NTOT * sizeof(int);
    int*   rp       = (int*)p;           p += (size_t)(NTOT + 1) * sizeof(int);
    int*   cur      = (int*)p;           p += (size_t)NTOT * sizeof(int);
    int*   partials = (int*)p;           p += (size_t)1024 * sizeof(int);

    const int NPART = (NTOT + SCAN_TILE - 1) / SCAN_TILE;

    dim3 eblk(256), egrd((2 * E + 255) / 256);
    dim3 fblk(256);
    dim3 fgrd_u((NU + 3) / 4), fgrd_i((NI + 3) / 4);
    int n4u = NU * C / 4, n4i = NI * C / 4;
    dim3 cgrd_u((n4u + 255) / 256), cgrd_i((n4i + 255) / 256);

    // ---- build combined CSR (by destination bucket) ----
    hipMemsetAsync(cnt, 0, (size_t)NTOT * sizeof(int), stream);
    count_kernel<<<egrd, eblk, 0, stream>>>(ei_iu, ei_ui, cnt, E, NU);
    scan_partials<<<NPART, 1024, 0, stream>>>(cnt, partials, NTOT);
    scan_spine<<<1, 1024, 0, stream>>>(partials, rp, NPART, NTOT);
    scan_write<<<NPART, 1024, 0, stream>>>(cnt, partials, rp, cur, NTOT);
    fill_kernel<<<egrd, eblk, 0, stream>>>(ei_iu, ew_iu, ei_ui, ew_ui, cur, csr, E, NU);

    // ---- bf16 snapshots of inputs for layer-0 gathers ----
    cvt_bf16_kernel<<<cgrd_u, fblk, 0, stream>>>(x_user, ub, n4u);
    cvt_bf16_kernel<<<cgrd_i, fblk, 0, stream>>>(x_item, ib, n4i);

    // ---- layer 0 (gather bf16 inputs, residual fp32 inputs) ----
    sage_ln_kernel<<<fgrd_u, fblk, 0, stream>>>(ib, x_user, rp,      csr, lnwu0, lnbu0, out_u, NU, 1);
    sage_ln_kernel<<<fgrd_i, fblk, 0, stream>>>(ub, x_item, rp + NU, csr, lnwi0, lnbi0, out_i, NI, 1);

    // ---- bf16 snapshots of layer-0 activations ----
    cvt_bf16_kernel<<<cgrd_u, fblk, 0, stream>>>(out_u, ub, n4u);
    cvt_bf16_kernel<<<cgrd_i, fblk, 0, stream>>>(out_i, ib, n4i);

    // ---- layer 1 (gather bf16 snapshots; residual + output in-place in d_out) ----
    sage_ln_kernel<<<fgrd_u, fblk, 0, stream>>>(ib, out_u, rp,      csr, lnwu1, lnbu1, out_u, NU, 0);
    sage_ln_kernel<<<fgrd_i, fblk, 0, stream>>>(ub, out_i, rp + NU, csr, lnwi1, lnbi1, out_i, NI, 0);
}